// Round 13
// baseline (3286.299 us; speedup 1.0000x reference)
//
#include <hip/hip_runtime.h>
#include <stdint.h>

#define B_    16
#define N_    8192
#define S_    1024
#define K_    32
#define D_    64
#define CIN   67          // 3 + D
#define C1    64
#define C3    128
#define FSTR  68          // feat row stride in floats (67 + 1 pad)
#define WSTR  65          // WT LDS stride (64+1): kills 64-way write conflicts
#define WSTR3 129         // l3 WT stride (128+1)
#define NP_   (B_*S_*K_)  // 524288 total grouped points
#define EPS_  1e-5f
#define FPT   256         // fps threads per block
#define NBB   8           // fps blocks per batch (all 128 blocks co-resident)
#define SHD   (N_/NBB)    // 1024 points per block shard
#define SPT   (SHD/FPT)   // 4 points per thread

typedef unsigned long long u64;
typedef unsigned int u32;

__device__ __forceinline__ u32 fmap(float f) {
  // monotonic float->uint mapping (handles tiny negatives from fp error)
  u32 u = __float_as_uint(f);
  u32 m = (u32)(((int)u) >> 31) | 0x80000000u;
  return u ^ m;
}

// DPP wave-64 reduce helpers (VALU-only; ctrl must be a compile-time constant,
// hence the template parameter — R7 compile-fail lesson).
template<int CTRL>
__device__ __forceinline__ float dpp_fmax(float v) {
  int t = __builtin_amdgcn_update_dpp(__float_as_int(v), __float_as_int(v),
                                      CTRL, 0xF, 0xF, false);
  return fmaxf(v, __int_as_float(t));
}
template<int CTRL>
__device__ __forceinline__ u32 dpp_umax(u32 v) {
  int t = __builtin_amdgcn_update_dpp((int)v, (int)v, CTRL, 0xF, 0xF, false);
  return ((u32)t > v) ? (u32)t : v;
}
template<int CTRL>
__device__ __forceinline__ u32 dpp_umin(u32 v) {
  int t = __builtin_amdgcn_update_dpp((int)v, (int)v, CTRL, 0xF, 0xF, false);
  return ((u32)t < v) ? (u32)t : v;
}
#define DPP_STAGES(v, OP) \
  { v = OP<0x111>(v); v = OP<0x112>(v); v = OP<0x114>(v); \
    v = OP<0x118>(v); v = OP<0x142>(v); v = OP<0x143>(v); }

// ---------------------------------------------------------------------------
// feat[b][n][0..2]=xyz, [3..66]=points, [67]=0 pad; pp[b][n] = |p|^2 (ref order)
__global__ __launch_bounds__(256) void feat_kernel(const float* __restrict__ xyz,
    const float* __restrict__ pts, float* __restrict__ feat, float* __restrict__ pp) {
  __shared__ float T[128*69];
  int b  = blockIdx.x >> 6;
  int n0 = (blockIdx.x & 63) * 128;
  int tid = threadIdx.x;
  for (int e = tid; e < CIN*128; e += 256) {
    int c = e >> 7, i = e & 127;
    float v = (c < 3) ? xyz[(size_t)(b*3 + c)*N_ + n0 + i]
                      : pts[(size_t)(b*D_ + (c-3))*N_ + n0 + i];
    T[i*69 + c] = v;
  }
  __syncthreads();
  for (int e = tid; e < 128*FSTR; e += 256) {
    int i = e / FSTR, c = e - i*FSTR;
    float v = (c < CIN) ? T[i*69 + c] : 0.f;
    feat[((size_t)(b*N_ + n0 + i))*FSTR + c] = v;
  }
  if (tid < 128) {
    float x = T[tid*69+0], y = T[tid*69+1], z = T[tid*69+2];
    pp[(size_t)b*N_ + n0 + tid] =
      __fadd_rn(__fadd_rn(__fmul_rn(x,x), __fmul_rn(y,y)), __fmul_rn(z,z));
  }
}

// ---------------------------------------------------------------------------
// FPS: NBB blocks per batch. Each block owns a SHD-point shard; full batch
// xyz staged in every block's LDS for centroid lookup. Per-step cross-block
// sync: tag-packed u64 partial-best published + polled with agent-scope
// atomics (XCD-safe; per-XCD L2s are not coherent). Tag = step t (10 bits);
// slots zeroed per launch by hipMemsetAsync so stale/poison never aliases.
// Key pack: (dist_bits<<23) | ((N-1-n)<<10) | t — max over equal tags
// selects max dist, ties -> lowest n (identical to single-block semantics).
__global__ __launch_bounds__(FPT) void fps_kernel(const float* __restrict__ xyz,
    float* __restrict__ nxyz, float* __restrict__ qq, float* __restrict__ out0,
    u64* part) {
  __shared__ float sx[N_], sy[N_], sz[N_];   // 96 KB
  __shared__ u64 lk[2][FPT/64];
  __shared__ int hist[S_];
  __shared__ int curs;
  int gb = blockIdx.x;
  int b = gb >> 3, blk = gb & (NBB-1);
  int tid = threadIdx.x;
  float px[SPT], py[SPT], pz[SPT], dist[SPT];
  for (int j = 0; j < N_/FPT; ++j) {       // stage full batch xyz
    int n = j*FPT + tid;
    sx[n] = xyz[(size_t)(b*3+0)*N_ + n];
    sy[n] = xyz[(size_t)(b*3+1)*N_ + n];
    sz[n] = xyz[(size_t)(b*3+2)*N_ + n];
  }
#pragma unroll
  for (int j = 0; j < SPT; ++j) dist[j] = 1e10f;
  if (tid == 0) hist[0] = 0;
  __syncthreads();
#pragma unroll
  for (int j = 0; j < SPT; ++j) {
    int n = blk*SHD + j*FPT + tid;
    px[j] = sx[n]; py[j] = sy[n]; pz[j] = sz[n];
  }
  float cx = sx[0], cy = sy[0], cz = sz[0];
  int wid = tid >> 6, lane = tid & 63;
  size_t pbase = (size_t)b*S_*NBB;
  for (int t = 1; t < S_; ++t) {
    float bv = -1.f;
#pragma unroll
    for (int j = 0; j < SPT; ++j) {
      float dx = __fsub_rn(px[j], cx), dy = __fsub_rn(py[j], cy), dz = __fsub_rn(pz[j], cz);
      float d = __fadd_rn(__fadd_rn(__fmul_rn(dx,dx), __fmul_rn(dy,dy)), __fmul_rn(dz,dz));
      float nd = fminf(dist[j], d);
      dist[j] = nd;
      bv = fmaxf(bv, nd);
    }
    int bj = 0;
#pragma unroll
    for (int j = SPT-1; j >= 0; --j) bj = (dist[j] == bv) ? j : bj;   // smallest j
    int bn = blk*SHD + bj*FPT + tid;
    // wave max value (DPP, VALU-only)
    float wv = bv;
    DPP_STAGES(wv, dpp_fmax);
    int Mv_i = __builtin_amdgcn_readlane(__float_as_int(wv), 63);
    float Mv = __int_as_float(Mv_i);
    u32 ix = (bv == Mv) ? (u32)(N_-1 - bn) : 0u;
    DPP_STAGES(ix, dpp_umax);
    u32 Mi = (u32)__builtin_amdgcn_readlane((int)ix, 63);
    // tag-packed wave key: dist[54:23] | idx[22:10] | t[9:0]
    u64 wkey = ((u64)(u32)Mv_i << 23) | ((u64)Mi << 10) | (u32)t;
    if (lane == 0) lk[t & 1][wid] = wkey;
    __syncthreads();
    if (tid == 0) {
      u64 Mb = lk[t & 1][0];
#pragma unroll
      for (int w = 1; w < FPT/64; ++w) { u64 o = lk[t & 1][w]; Mb = o > Mb ? o : Mb; }
      __hip_atomic_store(&part[pbase + (size_t)t*NBB + blk], Mb,
                         __ATOMIC_RELAXED, __HIP_MEMORY_SCOPE_AGENT);
      u64 M = Mb;
      u32 pend = 0xFFu & ~(1u << blk);
      while (pend) {
#pragma unroll
        for (int w = 0; w < NBB; ++w) {
          if (pend & (1u << w)) {
            u64 o = __hip_atomic_load(&part[pbase + (size_t)t*NBB + w],
                                      __ATOMIC_RELAXED, __HIP_MEMORY_SCOPE_AGENT);
            if ((u32)(o & 0x3FFu) == (u32)t) { M = o > M ? o : M; pend &= ~(1u << w); }
          }
        }
        if (pend) __builtin_amdgcn_s_sleep(1);
      }
      int cur = N_-1 - (int)((M >> 10) & 0x1FFFu);
      curs = cur;
      if (blk == 0) hist[t] = cur;
    }
    __syncthreads();
    int cur = curs;
    cx = sx[cur]; cy = sy[cur]; cz = sz[cur];
  }
  __syncthreads();
  if (blk == 0) {
    for (int s = tid; s < S_; s += FPT) {
      int n = hist[s];
      float x = sx[n], y = sy[n], z = sz[n];
      nxyz[(size_t)(b*S_ + s)*3 + 0] = x;
      nxyz[(size_t)(b*S_ + s)*3 + 1] = y;
      nxyz[(size_t)(b*S_ + s)*3 + 2] = z;
      qq[(size_t)b*S_ + s] =
        __fadd_rn(__fadd_rn(__fmul_rn(x,x), __fmul_rn(y,y)), __fmul_rn(z,z));
      out0[(size_t)(b*3+0)*S_ + s] = x;
      out0[(size_t)(b*3+1)*S_ + s] = y;
      out0[(size_t)(b*3+2)*S_ + s] = z;
    }
  }
}

// ---------------------------------------------------------------------------
// KNN: one block (256 thr) per query; 32 u64 keys/thread in regs; 32 rounds.
// (R12 version: block-wide extraction + ballot fast-path.)
__global__ __launch_bounds__(256) void knn_kernel(const float* __restrict__ xyz,
    const float* __restrict__ pp, const float* __restrict__ nxyz,
    const float* __restrict__ qq, int* __restrict__ knn_out) {
  __shared__ u64 lk[2][4];
  __shared__ u32 outl[K_];
  int q = blockIdx.x;          // b*S + s
  int b = q >> 10;
  int tid = threadIdx.x;
  float qx = nxyz[(size_t)q*3+0], qy = nxyz[(size_t)q*3+1], qz = nxyz[(size_t)q*3+2];
  float qv = qq[q];
  u64 key[32];
#pragma unroll
  for (int j = 0; j < 32; ++j) {
    int n = j*256 + tid;
    float px = xyz[(size_t)(b*3+0)*N_ + n];
    float py = xyz[(size_t)(b*3+1)*N_ + n];
    float pz = xyz[(size_t)(b*3+2)*N_ + n];
    float dot = __fadd_rn(__fadd_rn(__fmul_rn(qx,px), __fmul_rn(qy,py)), __fmul_rn(qz,pz));
    float d = __fsub_rn(__fadd_rn(qv, pp[(size_t)b*N_ + n]), __fmul_rn(2.0f, dot));
    key[j] = ((u64)fmap(d) << 32) | (u32)n;
  }
  u64 cm = key[0];
#pragma unroll
  for (int j = 1; j < 32; ++j) cm = key[j] < cm ? key[j] : cm;
  int wid = tid >> 6, lane = tid & 63;
  for (int r = 0; r < K_; ++r) {
    u32 cv = (u32)(cm >> 32), ci = (u32)(cm & 0xFFFFFFFFu);
    u32 wv = cv;
    DPP_STAGES(wv, dpp_umin);
    u32 Mv = (u32)__builtin_amdgcn_readlane((int)wv, 63);
    u64 bal = __ballot(cv == Mv);
    u32 Mi;
    if (__popcll(bal) == 1) {            // unique min-holder (common case)
      int ln = (int)__builtin_ctzll(bal);
      Mi = (u32)__builtin_amdgcn_readlane((int)ci, ln);
    } else {                             // exact tie: lowest n via DPP chain
      u32 ix = (cv == Mv) ? ci : 0xFFFFFFFFu;
      DPP_STAGES(ix, dpp_umin);
      Mi = (u32)__builtin_amdgcn_readlane((int)ix, 63);
    }
    u64 v = ((u64)Mv << 32) | Mi;
    if (lane == 0) lk[r & 1][wid] = v;
    __syncthreads();
    u64 M = lk[r & 1][0];
#pragma unroll
    for (int w = 1; w < 4; ++w) { u64 o = lk[r & 1][w]; M = o < M ? o : M; }
    if (tid == 0) outl[r] = (u32)(M & 0xFFFFFFFFu);
    if (cm == M) {                       // unique owner (key contains n)
#pragma unroll
      for (int j = 0; j < 32; ++j) key[j] = (key[j] == M) ? ~0ull : key[j];
      u64 m2 = key[0];
#pragma unroll
      for (int j = 1; j < 32; ++j) m2 = key[j] < m2 ? key[j] : m2;
      cm = m2;
    }
  }
  __syncthreads();
  if (tid < K_) knn_out[(size_t)q*K_ + tid] = (int)outl[tid];
}

// ---------------------------------------------------------------------------
// Layer 1: gather 67ch -> z1[p][64] + BN partial sums. 64 points/block.
__global__ __launch_bounds__(256) void l1_kernel(const float* __restrict__ feat,
    const float* __restrict__ nxyz, const int* __restrict__ knn_in,
    const float* __restrict__ W, const float* __restrict__ bias,
    float* __restrict__ z, float* __restrict__ part) {
  __shared__ float fT[FSTR*FSTR];     // [c][i], stride 68
  __shared__ float WT[CIN*WSTR];      // [c][o], stride 65 (bank-conflict-free)
  __shared__ float sst[2][4][C1];
  int p0 = blockIdx.x * 64, tid = threadIdx.x;
  for (int i = tid; i < C1*CIN; i += 256) {
    int o = i / CIN, c = i - o*CIN;
    WT[c*WSTR + o] = W[i];
  }
  {
    int i = tid >> 2, c4 = tid & 3;
    int p = p0 + i;
    int n = knn_in[p];
    int b = p >> 15;          // / (S*K)
    int bs = p >> 5;          // / K
    size_t base = ((size_t)(b*N_ + n))*FSTR;
    float qx = nxyz[(size_t)bs*3+0], qy = nxyz[(size_t)bs*3+1], qz = nxyz[(size_t)bs*3+2];
    for (int c4i = c4; c4i < 17; c4i += 4) {
      float4 v = *(const float4*)&feat[base + (size_t)c4i*4];
      if (c4i == 0) {
        v.x = __fsub_rn(v.x, qx); v.y = __fsub_rn(v.y, qy); v.z = __fsub_rn(v.z, qz);
      }
      int c = c4i*4;
      fT[(c+0)*FSTR + i] = v.x;
      fT[(c+1)*FSTR + i] = v.y;
      fT[(c+2)*FSTR + i] = v.z;
      fT[(c+3)*FSTR + i] = v.w;
    }
  }
  __syncthreads();
  int o = tid & 63, pg = tid >> 6, pb = pg*16;
  float acc[16];
  float bv = bias[o];
#pragma unroll
  for (int i = 0; i < 16; ++i) acc[i] = bv;
  for (int k = 0; k < CIN; ++k) {
    float w = WT[k*WSTR + o];
#pragma unroll
    for (int i4 = 0; i4 < 4; ++i4) {
      float4 f = *(const float4*)&fT[k*FSTR + pb + i4*4];
      acc[i4*4+0] = fmaf(w, f.x, acc[i4*4+0]);
      acc[i4*4+1] = fmaf(w, f.y, acc[i4*4+1]);
      acc[i4*4+2] = fmaf(w, f.z, acc[i4*4+2]);
      acc[i4*4+3] = fmaf(w, f.w, acc[i4*4+3]);
    }
  }
  float s1 = 0.f, s2 = 0.f;
#pragma unroll
  for (int i = 0; i < 16; ++i) {
    int p = p0 + pb + i;
    z[(size_t)p*C1 + o] = acc[i];
    s1 = __fadd_rn(s1, acc[i]);
    s2 = fmaf(acc[i], acc[i], s2);
  }
  sst[0][pg][o] = s1; sst[1][pg][o] = s2;
  __syncthreads();
  if (tid < C1) {
    float a = ((sst[0][0][tid] + sst[0][1][tid]) + sst[0][2][tid]) + sst[0][3][tid];
    float c = ((sst[1][0][tid] + sst[1][1][tid]) + sst[1][2][tid]) + sst[1][3][tid];
    part[(size_t)blockIdx.x*(2*C1) + tid]      = a;
    part[(size_t)blockIdx.x*(2*C1) + C1 + tid] = c;
  }
}

// ---------------------------------------------------------------------------
// Layer 2: in-place z -> BN1+ReLU -> GEMM(64x64) -> z  + BN2 partials.
__global__ __launch_bounds__(256) void l2_kernel(float* __restrict__ z,
    const float* __restrict__ W, const float* __restrict__ bias,
    const float* __restrict__ scale, const float* __restrict__ shift,
    float* __restrict__ part) {
  __shared__ float fT[C1*FSTR];
  __shared__ float WT[C1*WSTR];
  __shared__ float sst[2][4][C1];
  __shared__ float sc[C1], sh[C1];
  int p0 = blockIdx.x * 64, tid = threadIdx.x;
  if (tid < C1) { sc[tid] = scale[tid]; sh[tid] = shift[tid]; }
  for (int i = tid; i < C1*C1; i += 256) {
    int o = i >> 6, c = i & 63;
    WT[c*WSTR + o] = W[i];
  }
  __syncthreads();
  {
    int i = tid >> 2, c4 = tid & 3;
    const float4* zrow = (const float4*)&z[(size_t)(p0+i)*C1];
#pragma unroll
    for (int it = 0; it < 4; ++it) {
      int c4i = c4 + it*4;
      float4 v = zrow[c4i];
      int c = c4i*4;
      fT[(c+0)*FSTR + i] = fmaxf(0.f, fmaf(v.x, sc[c+0], sh[c+0]));
      fT[(c+1)*FSTR + i] = fmaxf(0.f, fmaf(v.y, sc[c+1], sh[c+1]));
      fT[(c+2)*FSTR + i] = fmaxf(0.f, fmaf(v.z, sc[c+2], sh[c+2]));
      fT[(c+3)*FSTR + i] = fmaxf(0.f, fmaf(v.w, sc[c+3], sh[c+3]));
    }
  }
  __syncthreads();
  int o = tid & 63, pg = tid >> 6, pb = pg*16;
  float acc[16];
  float bv = bias[o];
#pragma unroll
  for (int i = 0; i < 16; ++i) acc[i] = bv;
  for (int k = 0; k < C1; ++k) {
    float w = WT[k*WSTR + o];
#pragma unroll
    for (int i4 = 0; i4 < 4; ++i4) {
      float4 f = *(const float4*)&fT[k*FSTR + pb + i4*4];
      acc[i4*4+0] = fmaf(w, f.x, acc[i4*4+0]);
      acc[i4*4+1] = fmaf(w, f.y, acc[i4*4+1]);
      acc[i4*4+2] = fmaf(w, f.z, acc[i4*4+2]);
      acc[i4*4+3] = fmaf(w, f.w, acc[i4*4+3]);
    }
  }
  float s1 = 0.f, s2 = 0.f;
#pragma unroll
  for (int i = 0; i < 16; ++i) {
    int p = p0 + pb + i;
    z[(size_t)p*C1 + o] = acc[i];
    s1 = __fadd_rn(s1, acc[i]);
    s2 = fmaf(acc[i], acc[i], s2);
  }
  sst[0][pg][o] = s1; sst[1][pg][o] = s2;
  __syncthreads();
  if (tid < C1) {
    float a = ((sst[0][0][tid] + sst[0][1][tid]) + sst[0][2][tid]) + sst[0][3][tid];
    float c = ((sst[1][0][tid] + sst[1][1][tid]) + sst[1][2][tid]) + sst[1][3][tid];
    part[(size_t)blockIdx.x*(2*C1) + tid]      = a;
    part[(size_t)blockIdx.x*(2*C1) + C1 + tid] = c;
  }
}

// ---------------------------------------------------------------------------
// Layer 3: BN2+ReLU -> GEMM(64->128) -> max/min pool over k + BN3 partials.
__global__ __launch_bounds__(256) void l3_kernel(const float* __restrict__ z,
    const float* __restrict__ W, const float* __restrict__ bias,
    const float* __restrict__ scale, const float* __restrict__ shift,
    float* __restrict__ pmax, float* __restrict__ pmin, float* __restrict__ part) {
  __shared__ float fT[C1*FSTR];
  __shared__ float WT[C1*WSTR3];      // [c][o], stride 129
  __shared__ float sst[2][2][C3];
  __shared__ float sc[C1], sh[C1];
  int p0 = blockIdx.x * 64, tid = threadIdx.x;
  if (tid < C1) { sc[tid] = scale[tid]; sh[tid] = shift[tid]; }
  for (int i = tid; i < C3*C1; i += 256) {
    int o = i >> 6, c = i & 63;
    WT[c*WSTR3 + o] = W[i];
  }
  __syncthreads();
  {
    int i = tid >> 2, c4 = tid & 3;
    const float4* zrow = (const float4*)&z[(size_t)(p0+i)*C1];
#pragma unroll
    for (int it = 0; it < 4; ++it) {
      int c4i = c4 + it*4;
      float4 v = zrow[c4i];
      int c = c4i*4;
      fT[(c+0)*FSTR + i] = fmaxf(0.f, fmaf(v.x, sc[c+0], sh[c+0]));
      fT[(c+1)*FSTR + i] = fmaxf(0.f, fmaf(v.y, sc[c+1], sh[c+1]));
      fT[(c+2)*FSTR + i] = fmaxf(0.f, fmaf(v.z, sc[c+2], sh[c+2]));
      fT[(c+3)*FSTR + i] = fmaxf(0.f, fmaf(v.w, sc[c+3], sh[c+3]));
    }
  }
  __syncthreads();
  int o = tid & 127, g = tid >> 7, pb = g*32;
  float acc[32];
  float bv = bias[o];
#pragma unroll
  for (int i = 0; i < 32; ++i) acc[i] = bv;
  for (int k = 0; k < C1; ++k) {
    float w = WT[k*WSTR3 + o];
#pragma unroll
    for (int i4 = 0; i4 < 8; ++i4) {
      float4 f = *(const float4*)&fT[k*FSTR + pb + i4*4];
      acc[i4*4+0] = fmaf(w, f.x, acc[i4*4+0]);
      acc[i4*4+1] = fmaf(w, f.y, acc[i4*4+1]);
      acc[i4*4+2] = fmaf(w, f.z, acc[i4*4+2]);
      acc[i4*4+3] = fmaf(w, f.w, acc[i4*4+3]);
    }
  }
  float mx = acc[0], mn = acc[0], s1 = 0.f, s2 = 0.f;
#pragma unroll
  for (int i = 0; i < 32; ++i) {
    mx = fmaxf(mx, acc[i]);
    mn = fminf(mn, acc[i]);
    s1 = __fadd_rn(s1, acc[i]);
    s2 = fmaf(acc[i], acc[i], s2);
  }
  int bs = (p0 >> 5) + g;
  pmax[(size_t)bs*C3 + o] = mx;
  pmin[(size_t)bs*C3 + o] = mn;
  sst[0][g][o] = s1; sst[1][g][o] = s2;
  __syncthreads();
  if (tid < C3) {
    part[(size_t)blockIdx.x*(2*C3) + tid]      = sst[0][0][tid] + sst[0][1][tid];
    part[(size_t)blockIdx.x*(2*C3) + C3 + tid] = sst[1][0][tid] + sst[1][1][tid];
  }
}

// ---------------------------------------------------------------------------
// Deterministic BN stat reduce: one block per channel -> scale/shift.
template<int C>
__global__ __launch_bounds__(256) void red_kernel(const float* __restrict__ part,
    int nblk, const float* __restrict__ g, const float* __restrict__ be,
    float* __restrict__ scale, float* __restrict__ shift) {
  __shared__ float r1[256], r2[256];
  int o = blockIdx.x, tid = threadIdx.x;
  float s1 = 0.f, s2 = 0.f;
  for (int j = tid; j < nblk; j += 256) {
    s1 += part[(size_t)j*(2*C) + o];
    s2 += part[(size_t)j*(2*C) + C + o];
  }
  r1[tid] = s1; r2[tid] = s2;
  __syncthreads();
  for (int off = 128; off > 0; off >>= 1) {
    if (tid < off) { r1[tid] += r1[tid+off]; r2[tid] += r2[tid+off]; }
    __syncthreads();
  }
  if (tid == 0) {
    float cnt = (float)NP_;
    float mean = r1[0] / cnt;
    float var  = fmaxf(r2[0] / cnt - mean*mean, 0.f);
    float s = g[o] / sqrtf(var + EPS_);
    scale[o] = s;
    shift[o] = be[o] - mean * s;
  }
}

// ---------------------------------------------------------------------------
// Final: BN3+ReLU applied to pooled value (max if scale>=0 else min), transposed.
__global__ __launch_bounds__(256) void final_kernel(const float* __restrict__ pmax,
    const float* __restrict__ pmin, const float* __restrict__ scale,
    const float* __restrict__ shift, float* __restrict__ out1) {
  int i = blockIdx.x*256 + threadIdx.x;       // over B*C3*S
  if (i >= B_*C3*S_) return;
  int s = i & 1023;
  int o = (i >> 10) & 127;
  int b = i >> 17;
  int bs = b*S_ + s;
  float sc = scale[o], sh = shift[o];
  float v = (sc >= 0.f) ? pmax[(size_t)bs*C3 + o] : pmin[(size_t)bs*C3 + o];
  out1[i] = fmaxf(0.f, __fadd_rn(__fmul_rn(v, sc), sh));
}

// ---------------------------------------------------------------------------
extern "C" void kernel_launch(void* const* d_in, const int* in_sizes, int n_in,
                              void* d_out, int out_size, void* d_ws, size_t ws_size,
                              hipStream_t stream) {
  const float* xyz = (const float*)d_in[0];
  const float* pts = (const float*)d_in[1];
  const float* W0  = (const float*)d_in[2];
  const float* b0  = (const float*)d_in[3];
  const float* g0  = (const float*)d_in[4];
  const float* be0 = (const float*)d_in[5];
  const float* W1  = (const float*)d_in[6];
  const float* b1  = (const float*)d_in[7];
  const float* g1  = (const float*)d_in[8];
  const float* be1 = (const float*)d_in[9];
  const float* W2  = (const float*)d_in[10];
  const float* b2  = (const float*)d_in[11];
  const float* g2  = (const float*)d_in[12];
  const float* be2 = (const float*)d_in[13];

  float* ws = (float*)d_ws;
  size_t off = 0;
  float* feat = ws + off;  off += (size_t)B_*N_*FSTR;     // 8,912,896
  float* pp   = ws + off;  off += (size_t)B_*N_;          // 131,072
  float* nxyz = ws + off;  off += (size_t)B_*S_*3;        // 49,152
  float* qq   = ws + off;  off += (size_t)B_*S_;          // 16,384
  int*   knn  = (int*)(ws + off); off += (size_t)B_*S_*K_;// 524,288
  float* z    = ws + off;  off += (size_t)NP_*C1;         // 33,554,432
  float* part1 = ws + off; off += (size_t)8192*2*C1;      // 1,048,576
  float* part2 = ws + off; off += (size_t)8192*2*C1;
  float* part3 = ws + off; off += (size_t)8192*2*C3;      // 2,097,152
  float* pmax = ws + off;  off += (size_t)B_*S_*C3;       // 2,097,152
  float* pmin = ws + off;  off += (size_t)B_*S_*C3;
  float* sc1 = ws + off; off += C1;  float* sh1 = ws + off; off += C1;
  float* sc2 = ws + off; off += C1;  float* sh2 = ws + off; off += C1;
  float* sc3 = ws + off; off += C3;  float* sh3 = ws + off; off += C3;
  u64* fpart = (u64*)(ws + off); off += (size_t)B_*S_*NBB*2;  // 1 MB sync slots
  (void)ws_size; (void)in_sizes; (void)n_in; (void)out_size;

  float* out0 = (float*)d_out;              // [B,3,S]
  float* out1 = out0 + (size_t)B_*3*S_;     // [B,C3,S]

  hipMemsetAsync(fpart, 0, (size_t)B_*S_*NBB*sizeof(u64), stream);
  feat_kernel<<<dim3(B_*64), dim3(256), 0, stream>>>(xyz, pts, feat, pp);
  fps_kernel<<<dim3(B_*NBB), dim3(FPT), 0, stream>>>(xyz, nxyz, qq, out0, fpart);
  knn_kernel<<<dim3(B_*S_), dim3(256), 0, stream>>>(xyz, pp, nxyz, qq, knn);
  l1_kernel<<<dim3(NP_/64), dim3(256), 0, stream>>>(feat, nxyz, knn, W0, b0, z, part1);
  red_kernel<C1><<<dim3(C1), dim3(256), 0, stream>>>(part1, NP_/64, g0, be0, sc1, sh1);
  l2_kernel<<<dim3(NP_/64), dim3(256), 0, stream>>>(z, W1, b1, sc1, sh1, part2);
  red_kernel<C1><<<dim3(C1), dim3(256), 0, stream>>>(part2, NP_/64, g1, be1, sc2, sh2);
  l3_kernel<<<dim3(NP_/64), dim3(256), 0, stream>>>(z, W2, b2, sc2, sh2, pmax, pmin, part3);
  red_kernel<C3><<<dim3(C3), dim3(256), 0, stream>>>(part3, NP_/64, g2, be2, sc3, sh3);
  final_kernel<<<dim3((B_*C3*S_ + 255)/256), dim3(256), 0, stream>>>(pmax, pmin, sc3, sh3, out1);
}

// Round 14
// 1975.829 us; speedup vs baseline: 1.6633x; 1.6633x over previous
//
#include <hip/hip_runtime.h>
#include <stdint.h>

#define B_    16
#define N_    8192
#define S_    1024
#define K_    32
#define D_    64
#define CIN   67          // 3 + D
#define C1    64
#define C3    128
#define FSTR  68          // feat row stride in floats (67 + 1 pad)
#define WSTR  65          // WT LDS stride (64+1): kills 64-way write conflicts
#define WSTR3 129         // l3 WT stride (128+1)
#define NP_   (B_*S_*K_)  // 524288 total grouped points
#define EPS_  1e-5f
#define FPT   256         // fps threads (4 waves = 1/SIMD: overhead paid once)
#define FPP   (N_/FPT)    // 32 points/thread

typedef unsigned long long u64;
typedef unsigned int u32;

__device__ __forceinline__ u32 fmap(float f) {
  // monotonic float->uint mapping (handles tiny negatives from fp error)
  u32 u = __float_as_uint(f);
  u32 m = (u32)(((int)u) >> 31) | 0x80000000u;
  return u ^ m;
}

// DPP wave-64 reduce helpers (VALU-only; ctrl must be a compile-time constant,
// hence the template parameter — R7 compile-fail lesson).
template<int CTRL>
__device__ __forceinline__ float dpp_fmax(float v) {
  int t = __builtin_amdgcn_update_dpp(__float_as_int(v), __float_as_int(v),
                                      CTRL, 0xF, 0xF, false);
  return fmaxf(v, __int_as_float(t));
}
template<int CTRL>
__device__ __forceinline__ u32 dpp_umax(u32 v) {
  int t = __builtin_amdgcn_update_dpp((int)v, (int)v, CTRL, 0xF, 0xF, false);
  return ((u32)t > v) ? (u32)t : v;
}
template<int CTRL>
__device__ __forceinline__ u32 dpp_umin(u32 v) {
  int t = __builtin_amdgcn_update_dpp((int)v, (int)v, CTRL, 0xF, 0xF, false);
  return ((u32)t < v) ? (u32)t : v;
}
#define DPP_STAGES(v, OP) \
  { v = OP<0x111>(v); v = OP<0x112>(v); v = OP<0x114>(v); \
    v = OP<0x118>(v); v = OP<0x142>(v); v = OP<0x143>(v); }

// ---------------------------------------------------------------------------
// Fused FPS + feat dispatch. Blocks [0,B_) run FPS (R10-proven: 1 block/batch,
// 256 thr, 32 pts/thread, DPP reduce + LDS tree — latency floor ~938 µs on 16
// CUs). Blocks [B_, B_+B_*64) run the feat transpose on the other 240 CUs,
// fully hidden under fps's shadow. sbuf is aliased by both branches (disjoint
// per block): fps = sx/sy/sz xyz stage (98 KB); feat = 128x69 tile (35 KB).
// feat[b][n][0..2]=xyz, [3..66]=points, [67]=0 pad; pp[b][n]=|p|^2 (ref order)
__global__ __launch_bounds__(FPT) void fps_feat_kernel(
    const float* __restrict__ xyz, const float* __restrict__ pts,
    float* __restrict__ feat, float* __restrict__ pp,
    float* __restrict__ nxyz, float* __restrict__ qq, float* __restrict__ out0) {
  __shared__ float sbuf[3*N_];               // 96 KB, aliased by both branches
  __shared__ u64 lk[2][FPT/64];
  __shared__ int hist[S_];
  int tid = threadIdx.x;

  if (blockIdx.x < B_) {
    // ----------------------------- FPS branch -----------------------------
    float* sx = sbuf; float* sy = sbuf + N_; float* sz = sbuf + 2*N_;
    int b = blockIdx.x;
    float px[FPP], py[FPP], pz[FPP], dist[FPP];
#pragma unroll
    for (int j = 0; j < FPP; ++j) {
      int n = j*FPT + tid;
      float x = xyz[(size_t)(b*3+0)*N_ + n];
      float y = xyz[(size_t)(b*3+1)*N_ + n];
      float z = xyz[(size_t)(b*3+2)*N_ + n];
      px[j] = x; py[j] = y; pz[j] = z;
      sx[n] = x; sy[n] = y; sz[n] = z;
      dist[j] = 1e10f;
    }
    if (tid == 0) hist[0] = 0;
    __syncthreads();
    float cx = sx[0], cy = sy[0], cz = sz[0];
    int wid = tid >> 6, lane = tid & 63;
    for (int t = 1; t < S_; ++t) {
      float bv = -1.f;
#pragma unroll
      for (int j = 0; j < FPP; ++j) {
        float dx = __fsub_rn(px[j], cx), dy = __fsub_rn(py[j], cy), dz = __fsub_rn(pz[j], cz);
        float d = __fadd_rn(__fadd_rn(__fmul_rn(dx,dx), __fmul_rn(dy,dy)), __fmul_rn(dz,dz));
        float nd = fminf(dist[j], d);
        dist[j] = nd;
        bv = fmaxf(bv, nd);
      }
      int bj = 0;
#pragma unroll
      for (int j = FPP-1; j >= 0; --j) bj = (dist[j] == bv) ? j : bj;   // smallest j
      int bn = bj*FPT + tid;
      // wave max value (DPP, VALU-only), result in lane 63
      float wv = bv;
      DPP_STAGES(wv, dpp_fmax);
      int Mv_i = __builtin_amdgcn_readlane(__float_as_int(wv), 63);
      float Mv = __int_as_float(Mv_i);
      // tie-index: max of (N-1-bn) among lanes holding Mv -> lowest global n
      u32 ix = (bv == Mv) ? (u32)(N_-1 - bn) : 0u;
      DPP_STAGES(ix, dpp_umax);
      u32 Mi = (u32)__builtin_amdgcn_readlane((int)ix, 63);
      u64 best = ((u64)(u32)Mv_i << 32) | Mi;   // dist>=0: raw bits monotone
      if (lane == 0) lk[t & 1][wid] = best;
      __syncthreads();
      u64 M = lk[t & 1][0];
#pragma unroll
      for (int w = 1; w < FPT/64; ++w) { u64 o = lk[t & 1][w]; M = o > M ? o : M; }
      int cur = N_-1 - (int)(u32)(M & 0xFFFFFFFFu);
      cx = sx[cur]; cy = sy[cur]; cz = sz[cur];
      if (tid == 0) hist[t] = cur;
    }
    __syncthreads();
    for (int s = tid; s < S_; s += FPT) {
      int n = hist[s];
      float x = sx[n], y = sy[n], z = sz[n];
      nxyz[(size_t)(b*S_ + s)*3 + 0] = x;
      nxyz[(size_t)(b*S_ + s)*3 + 1] = y;
      nxyz[(size_t)(b*S_ + s)*3 + 2] = z;
      qq[(size_t)b*S_ + s] =
        __fadd_rn(__fadd_rn(__fmul_rn(x,x), __fmul_rn(y,y)), __fmul_rn(z,z));
      out0[(size_t)(b*3+0)*S_ + s] = x;
      out0[(size_t)(b*3+1)*S_ + s] = y;
      out0[(size_t)(b*3+2)*S_ + s] = z;
    }
  } else {
    // ----------------------------- feat branch ----------------------------
    float* T = sbuf;                         // 128*69 floats (35 KB < 96 KB)
    int bidx = blockIdx.x - B_;
    int b  = bidx >> 6;
    int n0 = (bidx & 63) * 128;
    for (int e = tid; e < CIN*128; e += 256) {
      int c = e >> 7, i = e & 127;
      float v = (c < 3) ? xyz[(size_t)(b*3 + c)*N_ + n0 + i]
                        : pts[(size_t)(b*D_ + (c-3))*N_ + n0 + i];
      T[i*69 + c] = v;
    }
    __syncthreads();
    for (int e = tid; e < 128*FSTR; e += 256) {
      int i = e / FSTR, c = e - i*FSTR;
      float v = (c < CIN) ? T[i*69 + c] : 0.f;
      feat[((size_t)(b*N_ + n0 + i))*FSTR + c] = v;
    }
    if (tid < 128) {
      float x = T[tid*69+0], y = T[tid*69+1], z = T[tid*69+2];
      pp[(size_t)b*N_ + n0 + tid] =
        __fadd_rn(__fadd_rn(__fmul_rn(x,x), __fmul_rn(y,y)), __fmul_rn(z,z));
    }
  }
}

// ---------------------------------------------------------------------------
// KNN: one block (256 thr) per query; 32 u64 keys/thread in regs; 32 rounds.
// (R10-proven: block-wide extraction, split-DPP chains, LDS tree.)
__global__ __launch_bounds__(256) void knn_kernel(const float* __restrict__ xyz,
    const float* __restrict__ pp, const float* __restrict__ nxyz,
    const float* __restrict__ qq, int* __restrict__ knn_out) {
  __shared__ u64 lk[2][4];
  __shared__ u32 outl[K_];
  int q = blockIdx.x;          // b*S + s
  int b = q >> 10;
  int tid = threadIdx.x;
  float qx = nxyz[(size_t)q*3+0], qy = nxyz[(size_t)q*3+1], qz = nxyz[(size_t)q*3+2];
  float qv = qq[q];
  u64 key[32];
#pragma unroll
  for (int j = 0; j < 32; ++j) {
    int n = j*256 + tid;
    float px = xyz[(size_t)(b*3+0)*N_ + n];
    float py = xyz[(size_t)(b*3+1)*N_ + n];
    float pz = xyz[(size_t)(b*3+2)*N_ + n];
    float dot = __fadd_rn(__fadd_rn(__fmul_rn(qx,px), __fmul_rn(qy,py)), __fmul_rn(qz,pz));
    float d = __fsub_rn(__fadd_rn(qv, pp[(size_t)b*N_ + n]), __fmul_rn(2.0f, dot));
    key[j] = ((u64)fmap(d) << 32) | (u32)n;
  }
  u64 cm = key[0];
#pragma unroll
  for (int j = 1; j < 32; ++j) cm = key[j] < cm ? key[j] : cm;
  int wid = tid >> 6, lane = tid & 63;
  for (int r = 0; r < K_; ++r) {
    u32 cv = (u32)(cm >> 32), ci = (u32)(cm & 0xFFFFFFFFu);
    u32 wv = cv;
    DPP_STAGES(wv, dpp_umin);
    u32 Mv = (u32)__builtin_amdgcn_readlane((int)wv, 63);
    u32 ix = (cv == Mv) ? ci : 0xFFFFFFFFu;
    DPP_STAGES(ix, dpp_umin);
    u32 Mi = (u32)__builtin_amdgcn_readlane((int)ix, 63);
    u64 v = ((u64)Mv << 32) | Mi;
    if (lane == 0) lk[r & 1][wid] = v;
    __syncthreads();
    u64 M = lk[r & 1][0];
#pragma unroll
    for (int w = 1; w < 4; ++w) { u64 o = lk[r & 1][w]; M = o < M ? o : M; }
    if (tid == 0) outl[r] = (u32)(M & 0xFFFFFFFFu);
    if (cm == M) {                       // unique owner (key contains n)
#pragma unroll
      for (int j = 0; j < 32; ++j) key[j] = (key[j] == M) ? ~0ull : key[j];
      u64 m2 = key[0];
#pragma unroll
      for (int j = 1; j < 32; ++j) m2 = key[j] < m2 ? key[j] : m2;
      cm = m2;
    }
  }
  __syncthreads();
  if (tid < K_) knn_out[(size_t)q*K_ + tid] = (int)outl[tid];
}

// ---------------------------------------------------------------------------
// Layer 1: gather 67ch -> z1[p][64] + BN partial sums. 64 points/block.
__global__ __launch_bounds__(256) void l1_kernel(const float* __restrict__ feat,
    const float* __restrict__ nxyz, const int* __restrict__ knn_in,
    const float* __restrict__ W, const float* __restrict__ bias,
    float* __restrict__ z, float* __restrict__ part) {
  __shared__ float fT[FSTR*FSTR];     // [c][i], stride 68
  __shared__ float WT[CIN*WSTR];      // [c][o], stride 65 (bank-conflict-free)
  __shared__ float sst[2][4][C1];
  int p0 = blockIdx.x * 64, tid = threadIdx.x;
  for (int i = tid; i < C1*CIN; i += 256) {
    int o = i / CIN, c = i - o*CIN;
    WT[c*WSTR + o] = W[i];
  }
  {
    int i = tid >> 2, c4 = tid & 3;
    int p = p0 + i;
    int n = knn_in[p];
    int b = p >> 15;          // / (S*K)
    int bs = p >> 5;          // / K
    size_t base = ((size_t)(b*N_ + n))*FSTR;
    float qx = nxyz[(size_t)bs*3+0], qy = nxyz[(size_t)bs*3+1], qz = nxyz[(size_t)bs*3+2];
    for (int c4i = c4; c4i < 17; c4i += 4) {
      float4 v = *(const float4*)&feat[base + (size_t)c4i*4];
      if (c4i == 0) {
        v.x = __fsub_rn(v.x, qx); v.y = __fsub_rn(v.y, qy); v.z = __fsub_rn(v.z, qz);
      }
      int c = c4i*4;
      fT[(c+0)*FSTR + i] = v.x;
      fT[(c+1)*FSTR + i] = v.y;
      fT[(c+2)*FSTR + i] = v.z;
      fT[(c+3)*FSTR + i] = v.w;
    }
  }
  __syncthreads();
  int o = tid & 63, pg = tid >> 6, pb = pg*16;
  float acc[16];
  float bv = bias[o];
#pragma unroll
  for (int i = 0; i < 16; ++i) acc[i] = bv;
  for (int k = 0; k < CIN; ++k) {
    float w = WT[k*WSTR + o];
#pragma unroll
    for (int i4 = 0; i4 < 4; ++i4) {
      float4 f = *(const float4*)&fT[k*FSTR + pb + i4*4];
      acc[i4*4+0] = fmaf(w, f.x, acc[i4*4+0]);
      acc[i4*4+1] = fmaf(w, f.y, acc[i4*4+1]);
      acc[i4*4+2] = fmaf(w, f.z, acc[i4*4+2]);
      acc[i4*4+3] = fmaf(w, f.w, acc[i4*4+3]);
    }
  }
  float s1 = 0.f, s2 = 0.f;
#pragma unroll
  for (int i = 0; i < 16; ++i) {
    int p = p0 + pb + i;
    z[(size_t)p*C1 + o] = acc[i];
    s1 = __fadd_rn(s1, acc[i]);
    s2 = fmaf(acc[i], acc[i], s2);
  }
  sst[0][pg][o] = s1; sst[1][pg][o] = s2;
  __syncthreads();
  if (tid < C1) {
    float a = ((sst[0][0][tid] + sst[0][1][tid]) + sst[0][2][tid]) + sst[0][3][tid];
    float c = ((sst[1][0][tid] + sst[1][1][tid]) + sst[1][2][tid]) + sst[1][3][tid];
    part[(size_t)blockIdx.x*(2*C1) + tid]      = a;
    part[(size_t)blockIdx.x*(2*C1) + C1 + tid] = c;
  }
}

// ---------------------------------------------------------------------------
// Layer 2: in-place z -> BN1+ReLU -> GEMM(64x64) -> z  + BN2 partials.
__global__ __launch_bounds__(256) void l2_kernel(float* __restrict__ z,
    const float* __restrict__ W, const float* __restrict__ bias,
    const float* __restrict__ scale, const float* __restrict__ shift,
    float* __restrict__ part) {
  __shared__ float fT[C1*FSTR];
  __shared__ float WT[C1*WSTR];
  __shared__ float sst[2][4][C1];
  __shared__ float sc[C1], sh[C1];
  int p0 = blockIdx.x * 64, tid = threadIdx.x;
  if (tid < C1) { sc[tid] = scale[tid]; sh[tid] = shift[tid]; }
  for (int i = tid; i < C1*C1; i += 256) {
    int o = i >> 6, c = i & 63;
    WT[c*WSTR + o] = W[i];
  }
  __syncthreads();
  {
    int i = tid >> 2, c4 = tid & 3;
    const float4* zrow = (const float4*)&z[(size_t)(p0+i)*C1];
#pragma unroll
    for (int it = 0; it < 4; ++it) {
      int c4i = c4 + it*4;
      float4 v = zrow[c4i];
      int c = c4i*4;
      fT[(c+0)*FSTR + i] = fmaxf(0.f, fmaf(v.x, sc[c+0], sh[c+0]));
      fT[(c+1)*FSTR + i] = fmaxf(0.f, fmaf(v.y, sc[c+1], sh[c+1]));
      fT[(c+2)*FSTR + i] = fmaxf(0.f, fmaf(v.z, sc[c+2], sh[c+2]));
      fT[(c+3)*FSTR + i] = fmaxf(0.f, fmaf(v.w, sc[c+3], sh[c+3]));
    }
  }
  __syncthreads();
  int o = tid & 63, pg = tid >> 6, pb = pg*16;
  float acc[16];
  float bv = bias[o];
#pragma unroll
  for (int i = 0; i < 16; ++i) acc[i] = bv;
  for (int k = 0; k < C1; ++k) {
    float w = WT[k*WSTR + o];
#pragma unroll
    for (int i4 = 0; i4 < 4; ++i4) {
      float4 f = *(const float4*)&fT[k*FSTR + pb + i4*4];
      acc[i4*4+0] = fmaf(w, f.x, acc[i4*4+0]);
      acc[i4*4+1] = fmaf(w, f.y, acc[i4*4+1]);
      acc[i4*4+2] = fmaf(w, f.z, acc[i4*4+2]);
      acc[i4*4+3] = fmaf(w, f.w, acc[i4*4+3]);
    }
  }
  float s1 = 0.f, s2 = 0.f;
#pragma unroll
  for (int i = 0; i < 16; ++i) {
    int p = p0 + pb + i;
    z[(size_t)p*C1 + o] = acc[i];
    s1 = __fadd_rn(s1, acc[i]);
    s2 = fmaf(acc[i], acc[i], s2);
  }
  sst[0][pg][o] = s1; sst[1][pg][o] = s2;
  __syncthreads();
  if (tid < C1) {
    float a = ((sst[0][0][tid] + sst[0][1][tid]) + sst[0][2][tid]) + sst[0][3][tid];
    float c = ((sst[1][0][tid] + sst[1][1][tid]) + sst[1][2][tid]) + sst[1][3][tid];
    part[(size_t)blockIdx.x*(2*C1) + tid]      = a;
    part[(size_t)blockIdx.x*(2*C1) + C1 + tid] = c;
  }
}

// ---------------------------------------------------------------------------
// Layer 3: BN2+ReLU -> GEMM(64->128) -> max/min pool over k + BN3 partials.
__global__ __launch_bounds__(256) void l3_kernel(const float* __restrict__ z,
    const float* __restrict__ W, const float* __restrict__ bias,
    const float* __restrict__ scale, const float* __restrict__ shift,
    float* __restrict__ pmax, float* __restrict__ pmin, float* __restrict__ part) {
  __shared__ float fT[C1*FSTR];
  __shared__ float WT[C1*WSTR3];      // [c][o], stride 129
  __shared__ float sst[2][2][C3];
  __shared__ float sc[C1], sh[C1];
  int p0 = blockIdx.x * 64, tid = threadIdx.x;
  if (tid < C1) { sc[tid] = scale[tid]; sh[tid] = shift[tid]; }
  for (int i = tid; i < C3*C1; i += 256) {
    int o = i >> 6, c = i & 63;
    WT[c*WSTR3 + o] = W[i];
  }
  __syncthreads();
  {
    int i = tid >> 2, c4 = tid & 3;
    const float4* zrow = (const float4*)&z[(size_t)(p0+i)*C1];
#pragma unroll
    for (int it = 0; it < 4; ++it) {
      int c4i = c4 + it*4;
      float4 v = zrow[c4i];
      int c = c4i*4;
      fT[(c+0)*FSTR + i] = fmaxf(0.f, fmaf(v.x, sc[c+0], sh[c+0]));
      fT[(c+1)*FSTR + i] = fmaxf(0.f, fmaf(v.y, sc[c+1], sh[c+1]));
      fT[(c+2)*FSTR + i] = fmaxf(0.f, fmaf(v.z, sc[c+2], sh[c+2]));
      fT[(c+3)*FSTR + i] = fmaxf(0.f, fmaf(v.w, sc[c+3], sh[c+3]));
    }
  }
  __syncthreads();
  int o = tid & 127, g = tid >> 7, pb = g*32;
  float acc[32];
  float bv = bias[o];
#pragma unroll
  for (int i = 0; i < 32; ++i) acc[i] = bv;
  for (int k = 0; k < C1; ++k) {
    float w = WT[k*WSTR3 + o];
#pragma unroll
    for (int i4 = 0; i4 < 8; ++i4) {
      float4 f = *(const float4*)&fT[k*FSTR + pb + i4*4];
      acc[i4*4+0] = fmaf(w, f.x, acc[i4*4+0]);
      acc[i4*4+1] = fmaf(w, f.y, acc[i4*4+1]);
      acc[i4*4+2] = fmaf(w, f.z, acc[i4*4+2]);
      acc[i4*4+3] = fmaf(w, f.w, acc[i4*4+3]);
    }
  }
  float mx = acc[0], mn = acc[0], s1 = 0.f, s2 = 0.f;
#pragma unroll
  for (int i = 0; i < 32; ++i) {
    mx = fmaxf(mx, acc[i]);
    mn = fminf(mn, acc[i]);
    s1 = __fadd_rn(s1, acc[i]);
    s2 = fmaf(acc[i], acc[i], s2);
  }
  int bs = (p0 >> 5) + g;
  pmax[(size_t)bs*C3 + o] = mx;
  pmin[(size_t)bs*C3 + o] = mn;
  sst[0][g][o] = s1; sst[1][g][o] = s2;
  __syncthreads();
  if (tid < C3) {
    part[(size_t)blockIdx.x*(2*C3) + tid]      = sst[0][0][tid] + sst[0][1][tid];
    part[(size_t)blockIdx.x*(2*C3) + C3 + tid] = sst[1][0][tid] + sst[1][1][tid];
  }
}

// ---------------------------------------------------------------------------
// Deterministic BN stat reduce: one block per channel -> scale/shift.
template<int C>
__global__ __launch_bounds__(256) void red_kernel(const float* __restrict__ part,
    int nblk, const float* __restrict__ g, const float* __restrict__ be,
    float* __restrict__ scale, float* __restrict__ shift) {
  __shared__ float r1[256], r2[256];
  int o = blockIdx.x, tid = threadIdx.x;
  float s1 = 0.f, s2 = 0.f;
  for (int j = tid; j < nblk; j += 256) {
    s1 += part[(size_t)j*(2*C) + o];
    s2 += part[(size_t)j*(2*C) + C + o];
  }
  r1[tid] = s1; r2[tid] = s2;
  __syncthreads();
  for (int off = 128; off > 0; off >>= 1) {
    if (tid < off) { r1[tid] += r1[tid+off]; r2[tid] += r2[tid+off]; }
    __syncthreads();
  }
  if (tid == 0) {
    float cnt = (float)NP_;
    float mean = r1[0] / cnt;
    float var  = fmaxf(r2[0] / cnt - mean*mean, 0.f);
    float s = g[o] / sqrtf(var + EPS_);
    scale[o] = s;
    shift[o] = be[o] - mean * s;
  }
}

// ---------------------------------------------------------------------------
// Final: BN3+ReLU applied to pooled value (max if scale>=0 else min), transposed.
__global__ __launch_bounds__(256) void final_kernel(const float* __restrict__ pmax,
    const float* __restrict__ pmin, const float* __restrict__ scale,
    const float* __restrict__ shift, float* __restrict__ out1) {
  int i = blockIdx.x*256 + threadIdx.x;       // over B*C3*S
  if (i >= B_*C3*S_) return;
  int s = i & 1023;
  int o = (i >> 10) & 127;
  int b = i >> 17;
  int bs = b*S_ + s;
  float sc = scale[o], sh = shift[o];
  float v = (sc >= 0.f) ? pmax[(size_t)bs*C3 + o] : pmin[(size_t)bs*C3 + o];
  out1[i] = fmaxf(0.f, __fadd_rn(__fmul_rn(v, sc), sh));
}

// ---------------------------------------------------------------------------
extern "C" void kernel_launch(void* const* d_in, const int* in_sizes, int n_in,
                              void* d_out, int out_size, void* d_ws, size_t ws_size,
                              hipStream_t stream) {
  const float* xyz = (const float*)d_in[0];
  const float* pts = (const float*)d_in[1];
  const float* W0  = (const float*)d_in[2];
  const float* b0  = (const float*)d_in[3];
  const float* g0  = (const float*)d_in[4];
  const float* be0 = (const float*)d_in[5];
  const float* W1  = (const float*)d_in[6];
  const float* b1  = (const float*)d_in[7];
  const float* g1  = (const float*)d_in[8];
  const float* be1 = (const float*)d_in[9];
  const float* W2  = (const float*)d_in[10];
  const float* b2  = (const float*)d_in[11];
  const float* g2  = (const float*)d_in[12];
  const float* be2 = (const float*)d_in[13];

  float* ws = (float*)d_ws;
  size_t off = 0;
  float* feat = ws + off;  off += (size_t)B_*N_*FSTR;     // 8,912,896
  float* pp   = ws + off;  off += (size_t)B_*N_;          // 131,072
  float* nxyz = ws + off;  off += (size_t)B_*S_*3;        // 49,152
  float* qq   = ws + off;  off += (size_t)B_*S_;          // 16,384
  int*   knn  = (int*)(ws + off); off += (size_t)B_*S_*K_;// 524,288
  float* z    = ws + off;  off += (size_t)NP_*C1;         // 33,554,432
  float* part1 = ws + off; off += (size_t)8192*2*C1;      // 1,048,576
  float* part2 = ws + off; off += (size_t)8192*2*C1;
  float* part3 = ws + off; off += (size_t)8192*2*C3;      // 2,097,152
  float* pmax = ws + off;  off += (size_t)B_*S_*C3;       // 2,097,152
  float* pmin = ws + off;  off += (size_t)B_*S_*C3;
  float* sc1 = ws + off; off += C1;  float* sh1 = ws + off; off += C1;
  float* sc2 = ws + off; off += C1;  float* sh2 = ws + off; off += C1;
  float* sc3 = ws + off; off += C3;  float* sh3 = ws + off; off += C3;
  (void)ws_size; (void)in_sizes; (void)n_in; (void)out_size;

  float* out0 = (float*)d_out;              // [B,3,S]
  float* out1 = out0 + (size_t)B_*3*S_;     // [B,C3,S]

  fps_feat_kernel<<<dim3(B_ + B_*64), dim3(FPT), 0, stream>>>(
      xyz, pts, feat, pp, nxyz, qq, out0);
  knn_kernel<<<dim3(B_*S_), dim3(256), 0, stream>>>(xyz, pp, nxyz, qq, knn);
  l1_kernel<<<dim3(NP_/64), dim3(256), 0, stream>>>(feat, nxyz, knn, W0, b0, z, part1);
  red_kernel<C1><<<dim3(C1), dim3(256), 0, stream>>>(part1, NP_/64, g0, be0, sc1, sh1);
  l2_kernel<<<dim3(NP_/64), dim3(256), 0, stream>>>(z, W1, b1, sc1, sh1, part2);
  red_kernel<C1><<<dim3(C1), dim3(256), 0, stream>>>(part2, NP_/64, g1, be1, sc2, sh2);
  l3_kernel<<<dim3(NP_/64), dim3(256), 0, stream>>>(z, W2, b2, sc2, sh2, pmax, pmin, part3);
  red_kernel<C3><<<dim3(C3), dim3(256), 0, stream>>>(part3, NP_/64, g2, be2, sc3, sh3);
  final_kernel<<<dim3((B_*C3*S_ + 255)/256), dim3(256), 0, stream>>>(pmax, pmin, sc3, sh3, out1);
}

// Round 16
// 1951.732 us; speedup vs baseline: 1.6838x; 1.0123x over previous
//
#include <hip/hip_runtime.h>
#include <stdint.h>

#define B_    16
#define N_    8192
#define S_    1024
#define K_    32
#define D_    64
#define CIN   67          // 3 + D
#define C1    64
#define C3    128
#define FSTR  68          // feat row stride in floats (67 + 1 pad)
#define WSTR  65          // WT LDS stride (64+1): kills 64-way write conflicts
#define WSTR3 129         // l3 WT stride (128+1)
#define NP_   (B_*S_*K_)  // 524288 total grouped points
#define EPS_  1e-5f
#define FPT   256         // fps threads (4 waves = 1/SIMD: overhead paid once)
#define FPP   (N_/FPT)    // 32 points/thread

typedef unsigned long long u64;
typedef unsigned int u32;

__device__ __forceinline__ u32 fmap(float f) {
  // monotonic float->uint mapping (handles tiny negatives from fp error)
  u32 u = __float_as_uint(f);
  u32 m = (u32)(((int)u) >> 31) | 0x80000000u;
  return u ^ m;
}

// DPP wave-64 reduce helpers (VALU-only; ctrl must be a compile-time constant,
// hence the template parameter — R7 compile-fail lesson).
template<int CTRL>
__device__ __forceinline__ float dpp_fmax(float v) {
  int t = __builtin_amdgcn_update_dpp(__float_as_int(v), __float_as_int(v),
                                      CTRL, 0xF, 0xF, false);
  return fmaxf(v, __int_as_float(t));
}
template<int CTRL>
__device__ __forceinline__ u32 dpp_umax(u32 v) {
  int t = __builtin_amdgcn_update_dpp((int)v, (int)v, CTRL, 0xF, 0xF, false);
  return ((u32)t > v) ? (u32)t : v;
}
template<int CTRL>
__device__ __forceinline__ u32 dpp_umin(u32 v) {
  int t = __builtin_amdgcn_update_dpp((int)v, (int)v, CTRL, 0xF, 0xF, false);
  return ((u32)t < v) ? (u32)t : v;
}
#define DPP_STAGES(v, OP) \
  { v = OP<0x111>(v); v = OP<0x112>(v); v = OP<0x114>(v); \
    v = OP<0x118>(v); v = OP<0x142>(v); v = OP<0x143>(v); }

// ---------------------------------------------------------------------------
// Fused FPS + feat dispatch (R14-proven). Blocks [0,B_) run FPS; blocks
// [B_, B_+B_*64) run the feat transpose on the other CUs, hidden under fps.
__global__ __launch_bounds__(FPT) void fps_feat_kernel(
    const float* __restrict__ xyz, const float* __restrict__ pts,
    float* __restrict__ feat, float* __restrict__ pp,
    float* __restrict__ nxyz, float* __restrict__ qq, float* __restrict__ out0) {
  __shared__ float sbuf[3*N_];               // 96 KB, aliased by both branches
  __shared__ u64 lk[2][FPT/64];
  __shared__ int hist[S_];
  int tid = threadIdx.x;

  if (blockIdx.x < B_) {
    // ----------------------------- FPS branch -----------------------------
    float* sx = sbuf; float* sy = sbuf + N_; float* sz = sbuf + 2*N_;
    int b = blockIdx.x;
    float px[FPP], py[FPP], pz[FPP], dist[FPP];
#pragma unroll
    for (int j = 0; j < FPP; ++j) {
      int n = j*FPT + tid;
      float x = xyz[(size_t)(b*3+0)*N_ + n];
      float y = xyz[(size_t)(b*3+1)*N_ + n];
      float z = xyz[(size_t)(b*3+2)*N_ + n];
      px[j] = x; py[j] = y; pz[j] = z;
      sx[n] = x; sy[n] = y; sz[n] = z;
      dist[j] = 1e10f;
    }
    if (tid == 0) hist[0] = 0;
    __syncthreads();
    float cx = sx[0], cy = sy[0], cz = sz[0];
    int wid = tid >> 6, lane = tid & 63;
    for (int t = 1; t < S_; ++t) {
      float bv = -1.f;
#pragma unroll
      for (int j = 0; j < FPP; ++j) {
        float dx = __fsub_rn(px[j], cx), dy = __fsub_rn(py[j], cy), dz = __fsub_rn(pz[j], cz);
        float d = __fadd_rn(__fadd_rn(__fmul_rn(dx,dx), __fmul_rn(dy,dy)), __fmul_rn(dz,dz));
        float nd = fminf(dist[j], d);
        dist[j] = nd;
        bv = fmaxf(bv, nd);
      }
      int bj = 0;
#pragma unroll
      for (int j = FPP-1; j >= 0; --j) bj = (dist[j] == bv) ? j : bj;   // smallest j
      int bn = bj*FPT + tid;
      float wv = bv;
      DPP_STAGES(wv, dpp_fmax);
      int Mv_i = __builtin_amdgcn_readlane(__float_as_int(wv), 63);
      float Mv = __int_as_float(Mv_i);
      u32 ix = (bv == Mv) ? (u32)(N_-1 - bn) : 0u;
      DPP_STAGES(ix, dpp_umax);
      u32 Mi = (u32)__builtin_amdgcn_readlane((int)ix, 63);
      u64 best = ((u64)(u32)Mv_i << 32) | Mi;   // dist>=0: raw bits monotone
      if (lane == 0) lk[t & 1][wid] = best;
      __syncthreads();
      u64 M = lk[t & 1][0];
#pragma unroll
      for (int w = 1; w < FPT/64; ++w) { u64 o = lk[t & 1][w]; M = o > M ? o : M; }
      int cur = N_-1 - (int)(u32)(M & 0xFFFFFFFFu);
      cx = sx[cur]; cy = sy[cur]; cz = sz[cur];
      if (tid == 0) hist[t] = cur;
    }
    __syncthreads();
    for (int s = tid; s < S_; s += FPT) {
      int n = hist[s];
      float x = sx[n], y = sy[n], z = sz[n];
      nxyz[(size_t)(b*S_ + s)*3 + 0] = x;
      nxyz[(size_t)(b*S_ + s)*3 + 1] = y;
      nxyz[(size_t)(b*S_ + s)*3 + 2] = z;
      qq[(size_t)b*S_ + s] =
        __fadd_rn(__fadd_rn(__fmul_rn(x,x), __fmul_rn(y,y)), __fmul_rn(z,z));
      out0[(size_t)(b*3+0)*S_ + s] = x;
      out0[(size_t)(b*3+1)*S_ + s] = y;
      out0[(size_t)(b*3+2)*S_ + s] = z;
    }
  } else {
    // ----------------------------- feat branch ----------------------------
    float* T = sbuf;                         // 128*69 floats (35 KB < 96 KB)
    int bidx = blockIdx.x - B_;
    int b  = bidx >> 6;
    int n0 = (bidx & 63) * 128;
    for (int e = tid; e < CIN*128; e += 256) {
      int c = e >> 7, i = e & 127;
      float v = (c < 3) ? xyz[(size_t)(b*3 + c)*N_ + n0 + i]
                        : pts[(size_t)(b*D_ + (c-3))*N_ + n0 + i];
      T[i*69 + c] = v;
    }
    __syncthreads();
    for (int e = tid; e < 128*FSTR; e += 256) {
      int i = e / FSTR, c = e - i*FSTR;
      float v = (c < CIN) ? T[i*69 + c] : 0.f;
      feat[((size_t)(b*N_ + n0 + i))*FSTR + c] = v;
    }
    if (tid < 128) {
      float x = T[tid*69+0], y = T[tid*69+1], z = T[tid*69+2];
      pp[(size_t)b*N_ + n0 + tid] =
        __fadd_rn(__fadd_rn(__fmul_rn(x,x), __fmul_rn(y,y)), __fmul_rn(z,z));
    }
  }
}

// ---------------------------------------------------------------------------
// KNN: one block (256 thr) per query; 32 u64 keys/thread in regs; 32 rounds.
// (R10-proven: block-wide extraction, split-DPP chains, LDS tree.)
__global__ __launch_bounds__(256) void knn_kernel(const float* __restrict__ xyz,
    const float* __restrict__ pp, const float* __restrict__ nxyz,
    const float* __restrict__ qq, int* __restrict__ knn_out) {
  __shared__ u64 lk[2][4];
  __shared__ u32 outl[K_];
  int q = blockIdx.x;          // b*S + s
  int b = q >> 10;
  int tid = threadIdx.x;
  float qx = nxyz[(size_t)q*3+0], qy = nxyz[(size_t)q*3+1], qz = nxyz[(size_t)q*3+2];
  float qv = qq[q];
  u64 key[32];
#pragma unroll
  for (int j = 0; j < 32; ++j) {
    int n = j*256 + tid;
    float px = xyz[(size_t)(b*3+0)*N_ + n];
    float py = xyz[(size_t)(b*3+1)*N_ + n];
    float pz = xyz[(size_t)(b*3+2)*N_ + n];
    float dot = __fadd_rn(__fadd_rn(__fmul_rn(qx,px), __fmul_rn(qy,py)), __fmul_rn(qz,pz));
    float d = __fsub_rn(__fadd_rn(qv, pp[(size_t)b*N_ + n]), __fmul_rn(2.0f, dot));
    key[j] = ((u64)fmap(d) << 32) | (u32)n;
  }
  u64 cm = key[0];
#pragma unroll
  for (int j = 1; j < 32; ++j) cm = key[j] < cm ? key[j] : cm;
  int wid = tid >> 6, lane = tid & 63;
  for (int r = 0; r < K_; ++r) {
    u32 cv = (u32)(cm >> 32), ci = (u32)(cm & 0xFFFFFFFFu);
    u32 wv = cv;
    DPP_STAGES(wv, dpp_umin);
    u32 Mv = (u32)__builtin_amdgcn_readlane((int)wv, 63);
    u32 ix = (cv == Mv) ? ci : 0xFFFFFFFFu;
    DPP_STAGES(ix, dpp_umin);
    u32 Mi = (u32)__builtin_amdgcn_readlane((int)ix, 63);
    u64 v = ((u64)Mv << 32) | Mi;
    if (lane == 0) lk[r & 1][wid] = v;
    __syncthreads();
    u64 M = lk[r & 1][0];
#pragma unroll
    for (int w = 1; w < 4; ++w) { u64 o = lk[r & 1][w]; M = o < M ? o : M; }
    if (tid == 0) outl[r] = (u32)(M & 0xFFFFFFFFu);
    if (cm == M) {                       // unique owner (key contains n)
#pragma unroll
      for (int j = 0; j < 32; ++j) key[j] = (key[j] == M) ? ~0ull : key[j];
      u64 m2 = key[0];
#pragma unroll
      for (int j = 1; j < 32; ++j) m2 = key[j] < m2 ? key[j] : m2;
      cm = m2;
    }
  }
  __syncthreads();
  if (tid < K_) knn_out[(size_t)q*K_ + tid] = (int)outl[tid];
}

// ---------------------------------------------------------------------------
// Layer 1: gather 67ch -> z1[p][64] + BN partial sums. 64 points/block.
__global__ __launch_bounds__(256) void l1_kernel(const float* __restrict__ feat,
    const float* __restrict__ nxyz, const int* __restrict__ knn_in,
    const float* __restrict__ W, const float* __restrict__ bias,
    float* __restrict__ z, float* __restrict__ part) {
  __shared__ float fT[FSTR*FSTR];     // [c][i], stride 68
  __shared__ float WT[CIN*WSTR];      // [c][o], stride 65 (bank-conflict-free)
  __shared__ float sst[2][4][C1];
  int p0 = blockIdx.x * 64, tid = threadIdx.x;
  for (int i = tid; i < C1*CIN; i += 256) {
    int o = i / CIN, c = i - o*CIN;
    WT[c*WSTR + o] = W[i];
  }
  {
    int i = tid >> 2, c4 = tid & 3;
    int p = p0 + i;
    int n = knn_in[p];
    int b = p >> 15;          // / (S*K)
    int bs = p >> 5;          // / K
    size_t base = ((size_t)(b*N_ + n))*FSTR;
    float qx = nxyz[(size_t)bs*3+0], qy = nxyz[(size_t)bs*3+1], qz = nxyz[(size_t)bs*3+2];
    for (int c4i = c4; c4i < 17; c4i += 4) {
      float4 v = *(const float4*)&feat[base + (size_t)c4i*4];
      if (c4i == 0) {
        v.x = __fsub_rn(v.x, qx); v.y = __fsub_rn(v.y, qy); v.z = __fsub_rn(v.z, qz);
      }
      int c = c4i*4;
      fT[(c+0)*FSTR + i] = v.x;
      fT[(c+1)*FSTR + i] = v.y;
      fT[(c+2)*FSTR + i] = v.z;
      fT[(c+3)*FSTR + i] = v.w;
    }
  }
  __syncthreads();
  int o = tid & 63, pg = tid >> 6, pb = pg*16;
  float acc[16];
  float bv = bias[o];
#pragma unroll
  for (int i = 0; i < 16; ++i) acc[i] = bv;
  for (int k = 0; k < CIN; ++k) {
    float w = WT[k*WSTR + o];
#pragma unroll
    for (int i4 = 0; i4 < 4; ++i4) {
      float4 f = *(const float4*)&fT[k*FSTR + pb + i4*4];
      acc[i4*4+0] = fmaf(w, f.x, acc[i4*4+0]);
      acc[i4*4+1] = fmaf(w, f.y, acc[i4*4+1]);
      acc[i4*4+2] = fmaf(w, f.z, acc[i4*4+2]);
      acc[i4*4+3] = fmaf(w, f.w, acc[i4*4+3]);
    }
  }
  float s1 = 0.f, s2 = 0.f;
#pragma unroll
  for (int i = 0; i < 16; ++i) {
    int p = p0 + pb + i;
    z[(size_t)p*C1 + o] = acc[i];
    s1 = __fadd_rn(s1, acc[i]);
    s2 = fmaf(acc[i], acc[i], s2);
  }
  sst[0][pg][o] = s1; sst[1][pg][o] = s2;
  __syncthreads();
  if (tid < C1) {
    float a = ((sst[0][0][tid] + sst[0][1][tid]) + sst[0][2][tid]) + sst[0][3][tid];
    float c = ((sst[1][0][tid] + sst[1][1][tid]) + sst[1][2][tid]) + sst[1][3][tid];
    part[(size_t)blockIdx.x*(2*C1) + tid]      = a;
    part[(size_t)blockIdx.x*(2*C1) + C1 + tid] = c;
  }
}

// ---------------------------------------------------------------------------
// Layer 2: in-place z -> BN1+ReLU -> GEMM(64x64) -> z  + BN2 partials.
__global__ __launch_bounds__(256) void l2_kernel(float* __restrict__ z,
    const float* __restrict__ W, const float* __restrict__ bias,
    const float* __restrict__ scale, const float* __restrict__ shift,
    float* __restrict__ part) {
  __shared__ float fT[C1*FSTR];
  __shared__ float WT[C1*WSTR];
  __shared__ float sst[2][4][C1];
  __shared__ float sc[C1], sh[C1];
  int p0 = blockIdx.x * 64, tid = threadIdx.x;
  if (tid < C1) { sc[tid] = scale[tid]; sh[tid] = shift[tid]; }
  for (int i = tid; i < C1*C1; i += 256) {
    int o = i >> 6, c = i & 63;
    WT[c*WSTR + o] = W[i];
  }
  __syncthreads();
  {
    int i = tid >> 2, c4 = tid & 3;
    const float4* zrow = (const float4*)&z[(size_t)(p0+i)*C1];
#pragma unroll
    for (int it = 0; it < 4; ++it) {
      int c4i = c4 + it*4;
      float4 v = zrow[c4i];
      int c = c4i*4;
      fT[(c+0)*FSTR + i] = fmaxf(0.f, fmaf(v.x, sc[c+0], sh[c+0]));
      fT[(c+1)*FSTR + i] = fmaxf(0.f, fmaf(v.y, sc[c+1], sh[c+1]));
      fT[(c+2)*FSTR + i] = fmaxf(0.f, fmaf(v.z, sc[c+2], sh[c+2]));
      fT[(c+3)*FSTR + i] = fmaxf(0.f, fmaf(v.w, sc[c+3], sh[c+3]));
    }
  }
  __syncthreads();
  int o = tid & 63, pg = tid >> 6, pb = pg*16;
  float acc[16];
  float bv = bias[o];
#pragma unroll
  for (int i = 0; i < 16; ++i) acc[i] = bv;
  for (int k = 0; k < C1; ++k) {
    float w = WT[k*WSTR + o];
#pragma unroll
    for (int i4 = 0; i4 < 4; ++i4) {
      float4 f = *(const float4*)&fT[k*FSTR + pb + i4*4];
      acc[i4*4+0] = fmaf(w, f.x, acc[i4*4+0]);
      acc[i4*4+1] = fmaf(w, f.y, acc[i4*4+1]);
      acc[i4*4+2] = fmaf(w, f.z, acc[i4*4+2]);
      acc[i4*4+3] = fmaf(w, f.w, acc[i4*4+3]);
    }
  }
  float s1 = 0.f, s2 = 0.f;
#pragma unroll
  for (int i = 0; i < 16; ++i) {
    int p = p0 + pb + i;
    z[(size_t)p*C1 + o] = acc[i];
    s1 = __fadd_rn(s1, acc[i]);
    s2 = fmaf(acc[i], acc[i], s2);
  }
  sst[0][pg][o] = s1; sst[1][pg][o] = s2;
  __syncthreads();
  if (tid < C1) {
    float a = ((sst[0][0][tid] + sst[0][1][tid]) + sst[0][2][tid]) + sst[0][3][tid];
    float c = ((sst[1][0][tid] + sst[1][1][tid]) + sst[1][2][tid]) + sst[1][3][tid];
    part[(size_t)blockIdx.x*(2*C1) + tid]      = a;
    part[(size_t)blockIdx.x*(2*C1) + C1 + tid] = c;
  }
}

// ---------------------------------------------------------------------------
// Layer 3: BN2+ReLU -> GEMM(64->128) -> max/min pool over k + BN3 partials.
__global__ __launch_bounds__(256) void l3_kernel(const float* __restrict__ z,
    const float* __restrict__ W, const float* __restrict__ bias,
    const float* __restrict__ scale, const float* __restrict__ shift,
    float* __restrict__ pmax, float* __restrict__ pmin, float* __restrict__ part) {
  __shared__ float fT[C1*FSTR];
  __shared__ float WT[C1*WSTR3];      // [c][o], stride 129
  __shared__ float sst[2][2][C3];
  __shared__ float sc[C1], sh[C1];
  int p0 = blockIdx.x * 64, tid = threadIdx.x;
  if (tid < C1) { sc[tid] = scale[tid]; sh[tid] = shift[tid]; }
  for (int i = tid; i < C3*C1; i += 256) {
    int o = i >> 6, c = i & 63;
    WT[c*WSTR3 + o] = W[i];
  }
  __syncthreads();
  {
    int i = tid >> 2, c4 = tid & 3;
    const float4* zrow = (const float4*)&z[(size_t)(p0+i)*C1];
#pragma unroll
    for (int it = 0; it < 4; ++it) {
      int c4i = c4 + it*4;
      float4 v = zrow[c4i];
      int c = c4i*4;
      fT[(c+0)*FSTR + i] = fmaxf(0.f, fmaf(v.x, sc[c+0], sh[c+0]));
      fT[(c+1)*FSTR + i] = fmaxf(0.f, fmaf(v.y, sc[c+1], sh[c+1]));
      fT[(c+2)*FSTR + i] = fmaxf(0.f, fmaf(v.z, sc[c+2], sh[c+2]));
      fT[(c+3)*FSTR + i] = fmaxf(0.f, fmaf(v.w, sc[c+3], sh[c+3]));
    }
  }
  __syncthreads();
  int o = tid & 127, g = tid >> 7, pb = g*32;
  float acc[32];
  float bv = bias[o];
#pragma unroll
  for (int i = 0; i < 32; ++i) acc[i] = bv;
  for (int k = 0; k < C1; ++k) {
    float w = WT[k*WSTR3 + o];
#pragma unroll
    for (int i4 = 0; i4 < 8; ++i4) {
      float4 f = *(const float4*)&fT[k*FSTR + pb + i4*4];
      acc[i4*4+0] = fmaf(w, f.x, acc[i4*4+0]);
      acc[i4*4+1] = fmaf(w, f.y, acc[i4*4+1]);
      acc[i4*4+2] = fmaf(w, f.z, acc[i4*4+2]);
      acc[i4*4+3] = fmaf(w, f.w, acc[i4*4+3]);
    }
  }
  float mx = acc[0], mn = acc[0], s1 = 0.f, s2 = 0.f;
#pragma unroll
  for (int i = 0; i < 32; ++i) {
    mx = fmaxf(mx, acc[i]);
    mn = fminf(mn, acc[i]);
    s1 = __fadd_rn(s1, acc[i]);
    s2 = fmaf(acc[i], acc[i], s2);
  }
  int bs = (p0 >> 5) + g;
  pmax[(size_t)bs*C3 + o] = mx;
  pmin[(size_t)bs*C3 + o] = mn;
  sst[0][g][o] = s1; sst[1][g][o] = s2;
  __syncthreads();
  if (tid < C3) {
    part[(size_t)blockIdx.x*(2*C3) + tid]      = sst[0][0][tid] + sst[0][1][tid];
    part[(size_t)blockIdx.x*(2*C3) + C3 + tid] = sst[1][0][tid] + sst[1][1][tid];
  }
}

// ---------------------------------------------------------------------------
// Deterministic BN stat reduce: one block per channel -> scale/shift.
template<int C>
__global__ __launch_bounds__(256) void red_kernel(const float* __restrict__ part,
    int nblk, const float* __restrict__ g, const float* __restrict__ be,
    float* __restrict__ scale, float* __restrict__ shift) {
  __shared__ float r1[256], r2[256];
  int o = blockIdx.x, tid = threadIdx.x;
  float s1 = 0.f, s2 = 0.f;
  for (int j = tid; j < nblk; j += 256) {
    s1 += part[(size_t)j*(2*C) + o];
    s2 += part[(size_t)j*(2*C) + C + o];
  }
  r1[tid] = s1; r2[tid] = s2;
  __syncthreads();
  for (int off = 128; off > 0; off >>= 1) {
    if (tid < off) { r1[tid] += r1[tid+off]; r2[tid] += r2[tid+off]; }
    __syncthreads();
  }
  if (tid == 0) {
    float cnt = (float)NP_;
    float mean = r1[0] / cnt;
    float var  = fmaxf(r2[0] / cnt - mean*mean, 0.f);
    float s = g[o] / sqrtf(var + EPS_);
    scale[o] = s;
    shift[o] = be[o] - mean * s;
  }
}

// ---------------------------------------------------------------------------
// Final: BN3+ReLU applied to pooled value (max if scale>=0 else min), transposed.
__global__ __launch_bounds__(256) void final_kernel(const float* __restrict__ pmax,
    const float* __restrict__ pmin, const float* __restrict__ scale,
    const float* __restrict__ shift, float* __restrict__ out1) {
  int i = blockIdx.x*256 + threadIdx.x;       // over B*C3*S
  if (i >= B_*C3*S_) return;
  int s = i & 1023;
  int o = (i >> 10) & 127;
  int b = i >> 17;
  int bs = b*S_ + s;
  float sc = scale[o], sh = shift[o];
  float v = (sc >= 0.f) ? pmax[(size_t)bs*C3 + o] : pmin[(size_t)bs*C3 + o];
  out1[i] = fmaxf(0.f, __fadd_rn(__fmul_rn(v, sc), sh));
}

// ---------------------------------------------------------------------------
extern "C" void kernel_launch(void* const* d_in, const int* in_sizes, int n_in,
                              void* d_out, int out_size, void* d_ws, size_t ws_size,
                              hipStream_t stream) {
  const float* xyz = (const float*)d_in[0];
  const float* pts = (const float*)d_in[1];
  const float* W0  = (const float*)d_in[2];
  const float* b0  = (const float*)d_in[3];
  const float* g0  = (const float*)d_in[4];
  const float* be0 = (const float*)d_in[5];
  const float* W1  = (const float*)d_in[6];
  const float* b1  = (const float*)d_in[7];
  const float* g1  = (const float*)d_in[8];
  const float* be1 = (const float*)d_in[9];
  const float* W2  = (const float*)d_in[10];
  const float* b2  = (const float*)d_in[11];
  const float* g2  = (const float*)d_in[12];
  const float* be2 = (const float*)d_in[13];

  float* ws = (float*)d_ws;
  size_t off = 0;
  float* feat = ws + off;  off += (size_t)B_*N_*FSTR;     // 8,912,896
  float* pp   = ws + off;  off += (size_t)B_*N_;          // 131,072
  float* nxyz = ws + off;  off += (size_t)B_*S_*3;        // 49,152
  float* qq   = ws + off;  off += (size_t)B_*S_;          // 16,384
  int*   knn  = (int*)(ws + off); off += (size_t)B_*S_*K_;// 524,288
  float* z    = ws + off;  off += (size_t)NP_*C1;         // 33,554,432
  float* part1 = ws + off; off += (size_t)8192*2*C1;      // 1,048,576
  float* part2 = ws + off; off += (size_t)8192*2*C1;
  float* part3 = ws + off; off += (size_t)8192*2*C3;      // 2,097,152
  float* pmax = ws + off;  off += (size_t)B_*S_*C3;       // 2,097,152
  float* pmin = ws + off;  off += (size_t)B_*S_*C3;
  float* sc1 = ws + off; off += C1;  float* sh1 = ws + off; off += C1;
  float* sc2 = ws + off; off += C1;  float* sh2 = ws + off; off += C1;
  float* sc3 = ws + off; off += C3;  float* sh3 = ws + off; off += C3;
  (void)ws_size; (void)in_sizes; (void)n_in; (void)out_size;

  float* out0 = (float*)d_out;              // [B,3,S]
  float* out1 = out0 + (size_t)B_*3*S_;     // [B,C3,S]

  fps_feat_kernel<<<dim3(B_ + B_*64), dim3(FPT), 0, stream>>>(
      xyz, pts, feat, pp, nxyz, qq, out0);
  knn_kernel<<<dim3(B_*S_), dim3(256), 0, stream>>>(xyz, pp, nxyz, qq, knn);
  l1_kernel<<<dim3(NP_/64), dim3(256), 0, stream>>>(feat, nxyz, knn, W0, b0, z, part1);
  red_kernel<C1><<<dim3(C1), dim3(256), 0, stream>>>(part1, NP_/64, g0, be0, sc1, sh1);
  l2_kernel<<<dim3(NP_/64), dim3(256), 0, stream>>>(z, W1, b1, sc1, sh1, part2);
  red_kernel<C1><<<dim3(C1), dim3(256), 0, stream>>>(part2, NP_/64, g1, be1, sc2, sh2);
  l3_kernel<<<dim3(NP_/64), dim3(256), 0, stream>>>(z, W2, b2, sc2, sh2, pmax, pmin, part3);
  red_kernel<C3><<<dim3(C3), dim3(256), 0, stream>>>(part3, NP_/64, g2, be2, sc3, sh3);
  final_kernel<<<dim3((B_*C3*S_ + 255)/256), dim3(256), 0, stream>>>(pmax, pmin, sc3, sh3, out1);
}